// Round 2
// baseline (568.458 us; speedup 1.0000x reference)
//
#include <hip/hip_runtime.h>
#include <hip/hip_bf16.h>
#include <cmath>

using bf16 = __hip_bfloat16;
typedef __attribute__((ext_vector_type(8))) short short8;
typedef __attribute__((ext_vector_type(4))) float f32x4;

#define LDK 72   // 64 + 8 pad: breaks pow-2 bank strides, keeps 16B alignment

__device__ __forceinline__ float bf2f(bf16 v){ return __bfloat162float(v); }
__device__ __forceinline__ bf16 f2bf(float v){ return __float2bfloat16(v); }

// ---------------------------------------------------------------------------
// Fused cast+transpose: out_bf16[C][R] = (bf16)in_f32[R][C]; R,C multiples of 64
// ---------------------------------------------------------------------------
__global__ __launch_bounds__(256) void transpose_f32_bf16(
    const float* __restrict__ in, bf16* __restrict__ out, int R, int C)
{
    __shared__ __align__(16) bf16 tile[64][72];
    const int c0 = blockIdx.x * 64, r0 = blockIdx.y * 64;
    const int t = threadIdx.x;
    const int lr = t >> 3, lc = (t & 7) * 8;
    for (int p = 0; p < 2; ++p) {
        int r = p * 32 + lr;
        const float* src = in + (size_t)(r0 + r) * C + c0 + lc;
        float4 a = *(const float4*)src;
        float4 b = *(const float4*)(src + 4);
        tile[r][lc + 0] = f2bf(a.x); tile[r][lc + 1] = f2bf(a.y);
        tile[r][lc + 2] = f2bf(a.z); tile[r][lc + 3] = f2bf(a.w);
        tile[r][lc + 4] = f2bf(b.x); tile[r][lc + 5] = f2bf(b.y);
        tile[r][lc + 6] = f2bf(b.z); tile[r][lc + 7] = f2bf(b.w);
    }
    __syncthreads();
    for (int p = 0; p < 2; ++p) {
        int r = p * 32 + lr;                    // row within out tile (= col of in tile)
        short8 v;
        for (int j = 0; j < 8; ++j) v[j] = *(const short*)&tile[lc + j][r];
        *(short8*)(out + (size_t)(c0 + r) * R + r0 + lc) = v;
    }
}

// concat bq|bk|bv -> [3072] fp32
__global__ __launch_bounds__(256) void concat_bias(
    const float* __restrict__ bq, const float* __restrict__ bk,
    const float* __restrict__ bv, float* __restrict__ out)
{
    int i = blockIdx.x * 256 + threadIdx.x;    // 0..3071
    const float* src = (i < 1024) ? bq : ((i < 2048) ? bk : bv);
    out[i] = src[i & 1023];
}

// ---------------------------------------------------------------------------
// LayerNorm over D=1024, one block (256 thr) per row. fp32 in -> bf16 out.
// ---------------------------------------------------------------------------
__global__ __launch_bounds__(256) void layernorm_k(
    const float* __restrict__ x, const float* __restrict__ g,
    const float* __restrict__ bta, bf16* __restrict__ out)
{
    const int row = blockIdx.x, t = threadIdx.x;
    const float* xr = x + (size_t)row * 1024;
    float v[4], s1 = 0.f, s2 = 0.f;
    for (int j = 0; j < 4; ++j) {
        float f = xr[j * 256 + t];
        v[j] = f; s1 += f; s2 += f * f;
    }
    for (int d = 1; d < 64; d <<= 1) { s1 += __shfl_xor(s1, d); s2 += __shfl_xor(s2, d); }
    __shared__ float red[2][4];
    int wave = t >> 6, lane = t & 63;
    if (lane == 0) { red[0][wave] = s1; red[1][wave] = s2; }
    __syncthreads();
    s1 = red[0][0] + red[0][1] + red[0][2] + red[0][3];
    s2 = red[1][0] + red[1][1] + red[1][2] + red[1][3];
    float mean = s1 * (1.0f / 1024.0f);
    float var  = s2 * (1.0f / 1024.0f) - mean * mean;
    float rs   = rsqrtf(var + 1e-5f);
    bf16* orow = out + (size_t)row * 1024;
    for (int j = 0; j < 4; ++j) {
        int c = j * 256 + t;
        orow[c] = f2bf((v[j] - mean) * rs * g[c] + bta[c]);
    }
}

// ---------------------------------------------------------------------------
// GEMM: C[M,N] = A[M,K] @ Bt[N,K]^T + bias(fp32), fused epilogue.
// MODE 0: store bf16 v
// MODE 1: store fp32  v + res_f32                    -> h
// MODE 2: store bf16  gelu_exact(v)                  -> ff1
// MODE 3: store fp32  v + res_f32                    -> out0
// 128x128 tile, BK=64, 4 waves (2x2), 16x16x32 bf16 MFMA, 4x4 frags/wave.
// ---------------------------------------------------------------------------
template <int MODE>
__global__ __launch_bounds__(256) void gemm_bt(
    const bf16* __restrict__ A, const bf16* __restrict__ Bt,
    const float* __restrict__ bias, const float* __restrict__ res,
    void* __restrict__ C, int M, int N, int K)
{
    __shared__ __align__(16) bf16 As[128][LDK];
    __shared__ __align__(16) bf16 Bs[128][LDK];
    const int m0 = blockIdx.x * 128, n0 = blockIdx.y * 128;
    const int t = threadIdx.x;
    const int wave = t >> 6, lane = t & 63, lhi = lane >> 4, llo = lane & 15;
    const int wm = (wave & 1) * 64, wn = (wave >> 1) * 64;
    const int srow = t >> 3, scol = (t & 7) * 8;

    f32x4 acc[4][4];
    for (int i = 0; i < 4; ++i)
        for (int j = 0; j < 4; ++j) acc[i][j] = (f32x4){0.f, 0.f, 0.f, 0.f};

    for (int k0 = 0; k0 < K; k0 += 64) {
        __syncthreads();
        for (int p = 0; p < 4; ++p) {
            int r = p * 32 + srow;
            *(short8*)&As[r][scol] = *(const short8*)(A  + (size_t)(m0 + r) * K + k0 + scol);
            *(short8*)&Bs[r][scol] = *(const short8*)(Bt + (size_t)(n0 + r) * K + k0 + scol);
        }
        __syncthreads();
        for (int kk = 0; kk < 64; kk += 32) {
            short8 af[4], bfr[4];
            for (int i = 0; i < 4; ++i) {
                af[i]  = *(const short8*)&As[wm + i * 16 + llo][kk + lhi * 8];
                bfr[i] = *(const short8*)&Bs[wn + i * 16 + llo][kk + lhi * 8];
            }
            for (int mi = 0; mi < 4; ++mi)
                for (int ni = 0; ni < 4; ++ni)
                    acc[mi][ni] = __builtin_amdgcn_mfma_f32_16x16x32_bf16(
                        af[mi], bfr[ni], acc[mi][ni], 0, 0, 0);
        }
    }

    for (int mi = 0; mi < 4; ++mi)
        for (int ni = 0; ni < 4; ++ni) {
            int row = m0 + wm + mi * 16 + lhi * 4;
            int col = n0 + wn + ni * 16 + llo;
            float bcol = bias[col];
            for (int r = 0; r < 4; ++r) {
                size_t idx = (size_t)(row + r) * N + col;
                float v = acc[mi][ni][r] + bcol;
                if (MODE == 0) {
                    ((bf16*)C)[idx] = f2bf(v);
                } else if (MODE == 1) {
                    ((float*)C)[idx] = v + res[idx];
                } else if (MODE == 2) {
                    ((bf16*)C)[idx] = f2bf(0.5f * v * (1.0f + erff(v * 0.70710678118654752f)));
                } else {
                    ((float*)C)[idx] = v + res[idx];
                }
            }
        }
}

// ---------------------------------------------------------------------------
// Block-local attention: one block per (b, h, seq-block of 64).
// qkv: [8192][3072] bf16 (q | k | v each 1024 wide, head h at col h*64)
// attw: [2048][64][64] fp32 (output 1)   o: [8192][1024] bf16
// ---------------------------------------------------------------------------
__global__ __launch_bounds__(256) void attn_kernel(
    const bf16* __restrict__ qkv, float* __restrict__ attw, bf16* __restrict__ o)
{
    __shared__ __align__(16) bf16 qs[64][LDK];
    __shared__ __align__(16) bf16 ks[64][LDK];
    __shared__ __align__(16) bf16 vs[64][LDK];
    const int gid = blockIdx.x;                 // b*512 + h*32 + blk
    const int blk = gid & 31, h = (gid >> 5) & 15, b = gid >> 9;
    const int t = threadIdx.x, wave = t >> 6, lane = t & 63;
    const int lhi = lane >> 4, llo = lane & 15;
    const int srow = t >> 3, scol = (t & 7) * 8;

    for (int p = 0; p < 2; ++p) {
        int r = p * 32 + srow;
        const bf16* base = qkv + (size_t)(b * 2048 + blk * 64 + r) * 3072 + h * 64 + scol;
        *(short8*)&qs[r][scol] = *(const short8*)(base);
        *(short8*)&ks[r][scol] = *(const short8*)(base + 1024);
        *(short8*)&vs[r][scol] = *(const short8*)(base + 2048);
    }
    __syncthreads();

    // scores: wave handles q-rows [16*wave, 16*wave+16)
    f32x4 sacc[4];
    for (int j = 0; j < 4; ++j) sacc[j] = (f32x4){0.f, 0.f, 0.f, 0.f};
    for (int kk = 0; kk < 64; kk += 32) {
        short8 aq = *(const short8*)&qs[wave * 16 + llo][kk + lhi * 8];
        for (int j = 0; j < 4; ++j) {
            short8 bk = *(const short8*)&ks[j * 16 + llo][kk + lhi * 8];
            sacc[j] = __builtin_amdgcn_mfma_f32_16x16x32_bf16(aq, bk, sacc[j], 0, 0, 0);
        }
    }
    // softmax over 64 cols; row = 16*wave + 4*lhi + r lives in 16 lanes (llo) x 4 j
    float inv[4];
    for (int r = 0; r < 4; ++r) {
        float m = -1e30f;
        for (int j = 0; j < 4; ++j) m = fmaxf(m, sacc[j][r]);
        for (int d = 1; d < 16; d <<= 1) m = fmaxf(m, __shfl_xor(m, d));
        float s = 0.f;
        for (int j = 0; j < 4; ++j) {
            float e = expf((sacc[j][r] - m) * 0.125f);
            sacc[j][r] = e; s += e;
        }
        for (int d = 1; d < 16; d <<= 1) s += __shfl_xor(s, d);
        inv[r] = 1.0f / s;
    }
    __syncthreads();   // everyone done reading qs before we overwrite it with P
    const size_t wbase = (size_t)gid * 4096;
    for (int j = 0; j < 4; ++j)
        for (int r = 0; r < 4; ++r) {
            int row = wave * 16 + lhi * 4 + r, col = j * 16 + llo;
            float pw = sacc[j][r] * inv[r];
            qs[row][col] = f2bf(pw);            // P in A-operand source layout
            attw[wbase + row * 64 + col] = pw;  // output 1 (fp32)
        }
    __syncthreads();

    // O = P @ V
    f32x4 oacc[4];
    for (int nt = 0; nt < 4; ++nt) oacc[nt] = (f32x4){0.f, 0.f, 0.f, 0.f};
    for (int kk = 0; kk < 64; kk += 32) {
        short8 aw = *(const short8*)&qs[wave * 16 + llo][kk + lhi * 8];
        for (int nt = 0; nt < 4; ++nt) {
            short8 bv;
            for (int jj = 0; jj < 8; ++jj)
                bv[jj] = *(const short*)&vs[kk + lhi * 8 + jj][nt * 16 + llo];
            oacc[nt] = __builtin_amdgcn_mfma_f32_16x16x32_bf16(aw, bv, oacc[nt], 0, 0, 0);
        }
    }
    for (int nt = 0; nt < 4; ++nt)
        for (int r = 0; r < 4; ++r) {
            int row = wave * 16 + lhi * 4 + r, col = nt * 16 + llo;
            o[(size_t)(b * 2048 + blk * 64 + row) * 1024 + h * 64 + col] = f2bf(oacc[nt][r]);
        }
}

// ---------------------------------------------------------------------------
extern "C" void kernel_launch(void* const* d_in, const int* in_sizes, int n_in,
                              void* d_out, int out_size, void* d_ws, size_t ws_size,
                              hipStream_t stream)
{
    const float* hidden = (const float*)d_in[0];
    const float* ln1_g  = (const float*)d_in[1];
    const float* ln1_b  = (const float*)d_in[2];
    const float* ln2_g  = (const float*)d_in[3];
    const float* ln2_b  = (const float*)d_in[4];
    const float* wq = (const float*)d_in[5];  const float* bq = (const float*)d_in[6];
    const float* wk = (const float*)d_in[7];  const float* bk = (const float*)d_in[8];
    const float* wv = (const float*)d_in[9];  const float* bv = (const float*)d_in[10];
    const float* wo = (const float*)d_in[11]; const float* bo = (const float*)d_in[12];
    const float* w1 = (const float*)d_in[13]; const float* b1 = (const float*)d_in[14];
    const float* w2 = (const float*)d_in[15]; const float* b2 = (const float*)d_in[16];

    char* ws = (char*)d_ws;
    const size_t MB = 1u << 20;
    // layout (MiB): peak 105
    bf16*  wqkvT   = (bf16*)(ws +  0 * MB);  // [3072][1024]  6MB
    bf16*  woT     = (bf16*)(ws +  6 * MB);  // [1024][1024]  2MB
    bf16*  w1T     = (bf16*)(ws +  8 * MB);  // [4096][1024]  8MB
    bf16*  w2T     = (bf16*)(ws + 16 * MB);  // [1024][4096]  8MB
    float* biasQKV = (float*)(ws + 24 * MB); // 12KB
    bf16*  x       = (bf16*)(ws + 25 * MB);  // [8192][1024] 16MB (x1 then x2)
    bf16*  qkv     = (bf16*)(ws + 41 * MB);  // [8192][3072] 48MB (dead after attn)
    float* hbuf    = (float*)(ws + 41 * MB); // [8192][1024] fp32 32MB, overlays qkv
    bf16*  ffc     = (bf16*)(ws + 73 * MB);  // [4096][4096] 32MB chunk, overlays qkv tail+obuf
    bf16*  obuf    = (bf16*)(ws + 89 * MB);  // [8192][1024] 16MB (dead after gemm<1>)

    float* out0 = (float*)d_out;
    float* attw = (float*)d_out + (size_t)8192 * 1024;

    // 1. weights -> bf16, transposed to [N][K]
    transpose_f32_bf16<<<dim3(16, 16), 256, 0, stream>>>(wq, wqkvT,                 1024, 1024);
    transpose_f32_bf16<<<dim3(16, 16), 256, 0, stream>>>(wk, wqkvT + 1024 * 1024,   1024, 1024);
    transpose_f32_bf16<<<dim3(16, 16), 256, 0, stream>>>(wv, wqkvT + 2*1024*1024,   1024, 1024);
    transpose_f32_bf16<<<dim3(16, 16), 256, 0, stream>>>(wo, woT, 1024, 1024);
    transpose_f32_bf16<<<dim3(64, 16), 256, 0, stream>>>(w1, w1T, 1024, 4096);
    transpose_f32_bf16<<<dim3(16, 64), 256, 0, stream>>>(w2, w2T, 4096, 1024);
    concat_bias<<<12, 256, 0, stream>>>(bq, bk, bv, biasQKV);

    // 2. x1 = LN1(hidden)
    layernorm_k<<<8192, 256, 0, stream>>>(hidden, ln1_g, ln1_b, x);

    // 3. qkv = x1 @ [wq|wk|wv]^T + [bq|bk|bv]   (M=8192, N=3072, K=1024)
    gemm_bt<0><<<dim3(64, 24), 256, 0, stream>>>(x, wqkvT, biasQKV, nullptr, qkv,
                                                 8192, 3072, 1024);

    // 4. block attention -> attw (fp32, output 1), obuf (bf16)
    attn_kernel<<<2048, 256, 0, stream>>>(qkv, attw, obuf);

    // 5. h = obuf @ wo^T + bo + hidden   (fp32; qkv region is dead now)
    gemm_bt<1><<<dim3(64, 8), 256, 0, stream>>>(obuf, woT, bo, hidden, hbuf,
                                                8192, 1024, 1024);

    // 6. x2 = LN2(h)
    layernorm_k<<<8192, 256, 0, stream>>>(hbuf, ln2_g, ln2_b, x);

    // 7+8. FFN in two 4096-row chunks (ffc overlays dead qkv-tail + obuf)
    for (int c = 0; c < 2; ++c) {
        const size_t ro = (size_t)c * 4096 * 1024;
        gemm_bt<2><<<dim3(32, 32), 256, 0, stream>>>(x + ro, w1T, b1, nullptr, ffc,
                                                     4096, 4096, 1024);
        gemm_bt<3><<<dim3(32, 8), 256, 0, stream>>>(ffc, w2T, b2, hbuf + ro, out0 + ro,
                                                    4096, 1024, 4096);
    }
}

// Round 3
// 523.436 us; speedup vs baseline: 1.0860x; 1.0860x over previous
//
#include <hip/hip_runtime.h>
#include <hip/hip_bf16.h>
#include <cmath>

using bf16 = __hip_bfloat16;
typedef __attribute__((ext_vector_type(8))) short short8;
typedef __attribute__((ext_vector_type(4))) float f32x4;

#define LDK 72   // padded stride for the small hand-staged tiles (attn, transpose)

__device__ __forceinline__ float bf2f(bf16 v){ return __bfloat162float(v); }
__device__ __forceinline__ bf16 f2bf(float v){ return __float2bfloat16(v); }

// async global->LDS, 16B per lane. LDS dest = wave-uniform base + lane*16.
__device__ __forceinline__ void ld16(const void* g, void* l) {
    __builtin_amdgcn_global_load_lds(
        (const __attribute__((address_space(1))) void*)g,
        (__attribute__((address_space(3))) void*)l, 16, 0, 0);
}

// ---------------------------------------------------------------------------
// Fused cast+transpose: out_bf16[C][R] = (bf16)in_f32[R][C]; R,C multiples of 64
// ---------------------------------------------------------------------------
__global__ __launch_bounds__(256) void transpose_f32_bf16(
    const float* __restrict__ in, bf16* __restrict__ out, int R, int C)
{
    __shared__ __align__(16) bf16 tile[64][72];
    const int c0 = blockIdx.x * 64, r0 = blockIdx.y * 64;
    const int t = threadIdx.x;
    const int lr = t >> 3, lc = (t & 7) * 8;
    for (int p = 0; p < 2; ++p) {
        int r = p * 32 + lr;
        const float* src = in + (size_t)(r0 + r) * C + c0 + lc;
        float4 a = *(const float4*)src;
        float4 b = *(const float4*)(src + 4);
        tile[r][lc + 0] = f2bf(a.x); tile[r][lc + 1] = f2bf(a.y);
        tile[r][lc + 2] = f2bf(a.z); tile[r][lc + 3] = f2bf(a.w);
        tile[r][lc + 4] = f2bf(b.x); tile[r][lc + 5] = f2bf(b.y);
        tile[r][lc + 6] = f2bf(b.z); tile[r][lc + 7] = f2bf(b.w);
    }
    __syncthreads();
    for (int p = 0; p < 2; ++p) {
        int r = p * 32 + lr;                    // row within out tile (= col of in tile)
        short8 v;
        for (int j = 0; j < 8; ++j) v[j] = *(const short*)&tile[lc + j][r];
        *(short8*)(out + (size_t)(c0 + r) * R + r0 + lc) = v;
    }
}

// concat bq|bk|bv -> [3072] fp32
__global__ __launch_bounds__(256) void concat_bias(
    const float* __restrict__ bq, const float* __restrict__ bk,
    const float* __restrict__ bv, float* __restrict__ out)
{
    int i = blockIdx.x * 256 + threadIdx.x;    // 0..3071
    const float* src = (i < 1024) ? bq : ((i < 2048) ? bk : bv);
    out[i] = src[i & 1023];
}

// ---------------------------------------------------------------------------
// LayerNorm over D=1024, one block (256 thr) per row. fp32 in -> bf16 out.
// ---------------------------------------------------------------------------
__global__ __launch_bounds__(256) void layernorm_k(
    const float* __restrict__ x, const float* __restrict__ g,
    const float* __restrict__ bta, bf16* __restrict__ out)
{
    const int row = blockIdx.x, t = threadIdx.x;
    const float* xr = x + (size_t)row * 1024;
    float v[4], s1 = 0.f, s2 = 0.f;
    for (int j = 0; j < 4; ++j) {
        float f = xr[j * 256 + t];
        v[j] = f; s1 += f; s2 += f * f;
    }
    for (int d = 1; d < 64; d <<= 1) { s1 += __shfl_xor(s1, d); s2 += __shfl_xor(s2, d); }
    __shared__ float red[2][4];
    int wave = t >> 6, lane = t & 63;
    if (lane == 0) { red[0][wave] = s1; red[1][wave] = s2; }
    __syncthreads();
    s1 = red[0][0] + red[0][1] + red[0][2] + red[0][3];
    s2 = red[1][0] + red[1][1] + red[1][2] + red[1][3];
    float mean = s1 * (1.0f / 1024.0f);
    float var  = s2 * (1.0f / 1024.0f) - mean * mean;
    float rs   = rsqrtf(var + 1e-5f);
    bf16* orow = out + (size_t)row * 1024;
    for (int j = 0; j < 4; ++j) {
        int c = j * 256 + t;
        orow[c] = f2bf((v[j] - mean) * rs * g[c] + bta[c]);
    }
}

// ---------------------------------------------------------------------------
// GEMM: C[M,N] = A[M,K] @ Bt[N,K]^T + bias(fp32), fused epilogue.
// MODE 0: bf16 v | MODE 1: f32 v+res | MODE 2: bf16 gelu(v) | MODE 3: f32 v+res
// Tile TM x 128, BK=64, 4 waves (2x2), 16x16x32 bf16 MFMA.
// Staging: global_load_lds 16B/lane into UNPADDED LDS with XOR-swizzled
// column groups: logical chunk (r, g) lives at byte r*128 + (g^(r&7))*16.
// Stage side: lane L writes phys slot (r=base+L/8, L&7) <= global col group
// (L&7)^(L/8)  (base%8==0, so r&7 == L/8). Read side: group (g ^ (llo&7)).
// => ds_read_b128 conflicts drop from 16-way to 2-way (free, m136).
// ---------------------------------------------------------------------------
template <int MODE, int TM>
__global__ __launch_bounds__(256) void gemm_bt(
    const bf16* __restrict__ A, const bf16* __restrict__ Bt,
    const float* __restrict__ bias, const float* __restrict__ res,
    void* __restrict__ C, int M, int N, int K)
{
    constexpr int MI = TM / 32;                 // frags per wave in M
    __shared__ __align__(16) bf16 As[TM * 64];
    __shared__ __align__(16) bf16 Bs[128 * 64];
    const int m0 = blockIdx.x * TM, n0 = blockIdx.y * 128;
    const int t = threadIdx.x;
    const int wave = t >> 6, lane = t & 63, lhi = lane >> 4, llo = lane & 15;
    const int wm = (wave & 1) * (TM / 2), wn = (wave >> 1) * 64;
    const int lrow = lane >> 3;                  // 0..7
    const int lcolsw = ((lane & 7) ^ lrow) * 8;  // swizzled source col group

    f32x4 acc[MI][4];
    for (int i = 0; i < MI; ++i)
        for (int j = 0; j < 4; ++j) acc[i][j] = (f32x4){0.f, 0.f, 0.f, 0.f};

    for (int k0 = 0; k0 < K; k0 += 64) {
        __syncthreads();
        for (int p = 0; p < TM / 32; ++p) {
            int rb = wave * (TM / 4) + p * 8;
            ld16(A + (size_t)(m0 + rb + lrow) * K + (k0 + lcolsw), &As[rb * 64]);
        }
        for (int p = 0; p < 4; ++p) {
            int rb = wave * 32 + p * 8;
            ld16(Bt + (size_t)(n0 + rb + lrow) * K + (k0 + lcolsw), &Bs[rb * 64]);
        }
        __syncthreads();
        for (int kk = 0; kk < 64; kk += 32) {
            const int gb = kk >> 3;
            short8 af[MI], bfr[4];
            for (int i = 0; i < MI; ++i) {
                int row = wm + i * 16 + llo;
                af[i] = *(const short8*)&As[row * 64 + (((gb + lhi) ^ (llo & 7)) * 8)];
            }
            for (int i = 0; i < 4; ++i) {
                int row = wn + i * 16 + llo;
                bfr[i] = *(const short8*)&Bs[row * 64 + (((gb + lhi) ^ (llo & 7)) * 8)];
            }
            for (int mi = 0; mi < MI; ++mi)
                for (int ni = 0; ni < 4; ++ni)
                    acc[mi][ni] = __builtin_amdgcn_mfma_f32_16x16x32_bf16(
                        af[mi], bfr[ni], acc[mi][ni], 0, 0, 0);
        }
    }

    for (int mi = 0; mi < MI; ++mi)
        for (int ni = 0; ni < 4; ++ni) {
            int row = m0 + wm + mi * 16 + lhi * 4;
            int col = n0 + wn + ni * 16 + llo;
            float bcol = bias[col];
            for (int r = 0; r < 4; ++r) {
                size_t idx = (size_t)(row + r) * N + col;
                float v = acc[mi][ni][r] + bcol;
                if (MODE == 0) {
                    ((bf16*)C)[idx] = f2bf(v);
                } else if (MODE == 1) {
                    ((float*)C)[idx] = v + res[idx];
                } else if (MODE == 2) {
                    ((bf16*)C)[idx] = f2bf(0.5f * v * (1.0f + erff(v * 0.70710678118654752f)));
                } else {
                    ((float*)C)[idx] = v + res[idx];
                }
            }
        }
}

// ---------------------------------------------------------------------------
// Block-local attention: one block per (b, h, seq-block of 64).
// qkv: [8192][3072] bf16 (q | k | v each 1024 wide, head h at col h*64)
// attw: [2048][64][64] fp32 (output 1)   o: [8192][1024] bf16
// ---------------------------------------------------------------------------
__global__ __launch_bounds__(256) void attn_kernel(
    const bf16* __restrict__ qkv, float* __restrict__ attw, bf16* __restrict__ o)
{
    __shared__ __align__(16) bf16 qs[64][LDK];
    __shared__ __align__(16) bf16 ks[64][LDK];
    __shared__ __align__(16) bf16 vs[64][LDK];
    const int gid = blockIdx.x;                 // b*512 + h*32 + blk
    const int blk = gid & 31, h = (gid >> 5) & 15, b = gid >> 9;
    const int t = threadIdx.x, wave = t >> 6, lane = t & 63;
    const int lhi = lane >> 4, llo = lane & 15;
    const int srow = t >> 3, scol = (t & 7) * 8;

    for (int p = 0; p < 2; ++p) {
        int r = p * 32 + srow;
        const bf16* base = qkv + (size_t)(b * 2048 + blk * 64 + r) * 3072 + h * 64 + scol;
        *(short8*)&qs[r][scol] = *(const short8*)(base);
        *(short8*)&ks[r][scol] = *(const short8*)(base + 1024);
        *(short8*)&vs[r][scol] = *(const short8*)(base + 2048);
    }
    __syncthreads();

    // scores: wave handles q-rows [16*wave, 16*wave+16)
    f32x4 sacc[4];
    for (int j = 0; j < 4; ++j) sacc[j] = (f32x4){0.f, 0.f, 0.f, 0.f};
    for (int kk = 0; kk < 64; kk += 32) {
        short8 aq = *(const short8*)&qs[wave * 16 + llo][kk + lhi * 8];
        for (int j = 0; j < 4; ++j) {
            short8 bk = *(const short8*)&ks[j * 16 + llo][kk + lhi * 8];
            sacc[j] = __builtin_amdgcn_mfma_f32_16x16x32_bf16(aq, bk, sacc[j], 0, 0, 0);
        }
    }
    // softmax over 64 cols; row = 16*wave + 4*lhi + r lives in 16 lanes (llo) x 4 j
    float inv[4];
    for (int r = 0; r < 4; ++r) {
        float m = -1e30f;
        for (int j = 0; j < 4; ++j) m = fmaxf(m, sacc[j][r]);
        for (int d = 1; d < 16; d <<= 1) m = fmaxf(m, __shfl_xor(m, d));
        float s = 0.f;
        for (int j = 0; j < 4; ++j) {
            float e = expf((sacc[j][r] - m) * 0.125f);
            sacc[j][r] = e; s += e;
        }
        for (int d = 1; d < 16; d <<= 1) s += __shfl_xor(s, d);
        inv[r] = 1.0f / s;
    }
    __syncthreads();   // everyone done reading qs before we overwrite it with P
    const size_t wbase = (size_t)gid * 4096;
    for (int j = 0; j < 4; ++j)
        for (int r = 0; r < 4; ++r) {
            int row = wave * 16 + lhi * 4 + r, col = j * 16 + llo;
            float pw = sacc[j][r] * inv[r];
            qs[row][col] = f2bf(pw);            // P in A-operand source layout
            attw[wbase + row * 64 + col] = pw;  // output 1 (fp32)
        }
    __syncthreads();

    // O = P @ V
    f32x4 oacc[4];
    for (int nt = 0; nt < 4; ++nt) oacc[nt] = (f32x4){0.f, 0.f, 0.f, 0.f};
    for (int kk = 0; kk < 64; kk += 32) {
        short8 aw = *(const short8*)&qs[wave * 16 + llo][kk + lhi * 8];
        for (int nt = 0; nt < 4; ++nt) {
            short8 bv;
            for (int jj = 0; jj < 8; ++jj)
                bv[jj] = *(const short*)&vs[kk + lhi * 8 + jj][nt * 16 + llo];
            oacc[nt] = __builtin_amdgcn_mfma_f32_16x16x32_bf16(aw, bv, oacc[nt], 0, 0, 0);
        }
    }
    for (int nt = 0; nt < 4; ++nt)
        for (int r = 0; r < 4; ++r) {
            int row = wave * 16 + lhi * 4 + r, col = nt * 16 + llo;
            o[(size_t)(b * 2048 + blk * 64 + row) * 1024 + h * 64 + col] = f2bf(oacc[nt][r]);
        }
}

// ---------------------------------------------------------------------------
extern "C" void kernel_launch(void* const* d_in, const int* in_sizes, int n_in,
                              void* d_out, int out_size, void* d_ws, size_t ws_size,
                              hipStream_t stream)
{
    const float* hidden = (const float*)d_in[0];
    const float* ln1_g  = (const float*)d_in[1];
    const float* ln1_b  = (const float*)d_in[2];
    const float* ln2_g  = (const float*)d_in[3];
    const float* ln2_b  = (const float*)d_in[4];
    const float* wq = (const float*)d_in[5];  const float* bq = (const float*)d_in[6];
    const float* wk = (const float*)d_in[7];  const float* bk = (const float*)d_in[8];
    const float* wv = (const float*)d_in[9];  const float* bv = (const float*)d_in[10];
    const float* wo = (const float*)d_in[11]; const float* bo = (const float*)d_in[12];
    const float* w1 = (const float*)d_in[13]; const float* b1 = (const float*)d_in[14];
    const float* w2 = (const float*)d_in[15]; const float* b2 = (const float*)d_in[16];

    char* ws = (char*)d_ws;
    const size_t MB = 1u << 20;
    // layout (MiB): peak 105
    bf16*  wqkvT   = (bf16*)(ws +  0 * MB);  // [3072][1024]  6MB
    bf16*  woT     = (bf16*)(ws +  6 * MB);  // [1024][1024]  2MB
    bf16*  w1T     = (bf16*)(ws +  8 * MB);  // [4096][1024]  8MB
    bf16*  w2T     = (bf16*)(ws + 16 * MB);  // [1024][4096]  8MB
    float* biasQKV = (float*)(ws + 24 * MB); // 12KB
    bf16*  x       = (bf16*)(ws + 25 * MB);  // [8192][1024] 16MB (x1 then x2)
    bf16*  qkv     = (bf16*)(ws + 41 * MB);  // [8192][3072] 48MB (dead after attn)
    float* hbuf    = (float*)(ws + 41 * MB); // [8192][1024] fp32 32MB, overlays qkv
    bf16*  ffc     = (bf16*)(ws + 73 * MB);  // [4096][4096] 32MB chunk, overlays qkv tail+obuf
    bf16*  obuf    = (bf16*)(ws + 89 * MB);  // [8192][1024] 16MB (dead after gemm<1>)

    float* out0 = (float*)d_out;
    float* attw = (float*)d_out + (size_t)8192 * 1024;

    // 1. weights -> bf16, transposed to [N][K]
    transpose_f32_bf16<<<dim3(16, 16), 256, 0, stream>>>(wq, wqkvT,                 1024, 1024);
    transpose_f32_bf16<<<dim3(16, 16), 256, 0, stream>>>(wk, wqkvT + 1024 * 1024,   1024, 1024);
    transpose_f32_bf16<<<dim3(16, 16), 256, 0, stream>>>(wv, wqkvT + 2*1024*1024,   1024, 1024);
    transpose_f32_bf16<<<dim3(16, 16), 256, 0, stream>>>(wo, woT, 1024, 1024);
    transpose_f32_bf16<<<dim3(64, 16), 256, 0, stream>>>(w1, w1T, 1024, 4096);
    transpose_f32_bf16<<<dim3(16, 64), 256, 0, stream>>>(w2, w2T, 4096, 1024);
    concat_bias<<<12, 256, 0, stream>>>(bq, bk, bv, biasQKV);

    // 2. x1 = LN1(hidden)
    layernorm_k<<<8192, 256, 0, stream>>>(hidden, ln1_g, ln1_b, x);

    // 3. qkv = x1 @ [wq|wk|wv]^T + [bq|bk|bv]   (M=8192, N=3072, K=1024)
    gemm_bt<0, 128><<<dim3(64, 24), 256, 0, stream>>>(x, wqkvT, biasQKV, nullptr, qkv,
                                                      8192, 3072, 1024);

    // 4. block attention -> attw (fp32, output 1), obuf (bf16)
    attn_kernel<<<2048, 256, 0, stream>>>(qkv, attw, obuf);

    // 5. h = obuf @ wo^T + bo + hidden   (fp32; qkv region is dead now)
    //    TM=64 -> 1024 blocks (4/CU)
    gemm_bt<1, 64><<<dim3(128, 8), 256, 0, stream>>>(obuf, woT, bo, hidden, hbuf,
                                                     8192, 1024, 1024);

    // 6. x2 = LN2(h)
    layernorm_k<<<8192, 256, 0, stream>>>(hbuf, ln2_g, ln2_b, x);

    // 7+8. FFN in two 4096-row chunks (ffc overlays dead qkv-tail + obuf)
    for (int c = 0; c < 2; ++c) {
        const size_t ro = (size_t)c * 4096 * 1024;
        gemm_bt<2, 128><<<dim3(32, 32), 256, 0, stream>>>(x + ro, w1T, b1, nullptr, ffc,
                                                          4096, 4096, 1024);
        // TM=64 -> 512 blocks per chunk (2/CU) instead of 256 (1/CU)
        gemm_bt<3, 64><<<dim3(64, 8), 256, 0, stream>>>(ffc, w2T, b2, hbuf + ro, out0 + ro,
                                                        4096, 1024, 4096);
    }
}

// Round 4
// 472.337 us; speedup vs baseline: 1.2035x; 1.1082x over previous
//
#include <hip/hip_runtime.h>
#include <hip/hip_bf16.h>
#include <cmath>

using bf16 = __hip_bfloat16;
typedef __attribute__((ext_vector_type(8))) short short8;
typedef __attribute__((ext_vector_type(4))) float f32x4;

#define LDK 72   // padded stride for the small hand-staged tiles (attn, transpose)

__device__ __forceinline__ float bf2f(bf16 v){ return __bfloat162float(v); }
__device__ __forceinline__ bf16 f2bf(float v){ return __float2bfloat16(v); }

// async global->LDS, 16B per lane. LDS dest = wave-uniform base + lane*16.
__device__ __forceinline__ void ld16(const void* g, void* l) {
    __builtin_amdgcn_global_load_lds(
        (const __attribute__((address_space(1))) void*)g,
        (__attribute__((address_space(3))) void*)l, 16, 0, 0);
}

// exp2-based tanh-form GELU (~10 VALU ops vs ~28 for erff); |err| <~1e-3
__device__ __forceinline__ float gelu_f(float x) {
    float u = 0.7978845608028654f * x * (1.0f + 0.044715f * x * x);
    float e = __expf(2.0f * u);
    float t = 1.0f - 2.0f / (e + 1.0f);
    return 0.5f * x * (1.0f + t);
}

// ---------------------------------------------------------------------------
// Fused cast+transpose: out_bf16[C][R] = (bf16)in_f32[R][C]; R,C multiples of 64
// ---------------------------------------------------------------------------
__global__ __launch_bounds__(256) void transpose_f32_bf16(
    const float* __restrict__ in, bf16* __restrict__ out, int R, int C)
{
    __shared__ __align__(16) bf16 tile[64][72];
    const int c0 = blockIdx.x * 64, r0 = blockIdx.y * 64;
    const int t = threadIdx.x;
    const int lr = t >> 3, lc = (t & 7) * 8;
    for (int p = 0; p < 2; ++p) {
        int r = p * 32 + lr;
        const float* src = in + (size_t)(r0 + r) * C + c0 + lc;
        float4 a = *(const float4*)src;
        float4 b = *(const float4*)(src + 4);
        tile[r][lc + 0] = f2bf(a.x); tile[r][lc + 1] = f2bf(a.y);
        tile[r][lc + 2] = f2bf(a.z); tile[r][lc + 3] = f2bf(a.w);
        tile[r][lc + 4] = f2bf(b.x); tile[r][lc + 5] = f2bf(b.y);
        tile[r][lc + 6] = f2bf(b.z); tile[r][lc + 7] = f2bf(b.w);
    }
    __syncthreads();
    for (int p = 0; p < 2; ++p) {
        int r = p * 32 + lr;                    // row within out tile (= col of in tile)
        short8 v;
        for (int j = 0; j < 8; ++j) v[j] = *(const short*)&tile[lc + j][r];
        *(short8*)(out + (size_t)(c0 + r) * R + r0 + lc) = v;
    }
}

// concat bq|bk|bv -> [3072] fp32
__global__ __launch_bounds__(256) void concat_bias(
    const float* __restrict__ bq, const float* __restrict__ bk,
    const float* __restrict__ bv, float* __restrict__ out)
{
    int i = blockIdx.x * 256 + threadIdx.x;    // 0..3071
    const float* src = (i < 1024) ? bq : ((i < 2048) ? bk : bv);
    out[i] = src[i & 1023];
}

// ---------------------------------------------------------------------------
// LayerNorm over D=1024, one block (256 thr) per row. fp32 in -> bf16 out.
// ---------------------------------------------------------------------------
__global__ __launch_bounds__(256) void layernorm_k(
    const float* __restrict__ x, const float* __restrict__ g,
    const float* __restrict__ bta, bf16* __restrict__ out)
{
    const int row = blockIdx.x, t = threadIdx.x;
    const float* xr = x + (size_t)row * 1024;
    float v[4], s1 = 0.f, s2 = 0.f;
    for (int j = 0; j < 4; ++j) {
        float f = xr[j * 256 + t];
        v[j] = f; s1 += f; s2 += f * f;
    }
    for (int d = 1; d < 64; d <<= 1) { s1 += __shfl_xor(s1, d); s2 += __shfl_xor(s2, d); }
    __shared__ float red[2][4];
    int wave = t >> 6, lane = t & 63;
    if (lane == 0) { red[0][wave] = s1; red[1][wave] = s2; }
    __syncthreads();
    s1 = red[0][0] + red[0][1] + red[0][2] + red[0][3];
    s2 = red[1][0] + red[1][1] + red[1][2] + red[1][3];
    float mean = s1 * (1.0f / 1024.0f);
    float var  = s2 * (1.0f / 1024.0f) - mean * mean;
    float rs   = rsqrtf(var + 1e-5f);
    bf16* orow = out + (size_t)row * 1024;
    for (int j = 0; j < 4; ++j) {
        int c = j * 256 + t;
        orow[c] = f2bf((v[j] - mean) * rs * g[c] + bta[c]);
    }
}

// ---------------------------------------------------------------------------
// GEMM: C[M,N] = A[M,K] @ Bt[N,K]^T + bias(fp32), fused epilogue.
// MODE 0: bf16 v | MODE 1: f32 v+res | MODE 2: bf16 gelu(v) | MODE 3: f32 v+res
// Tile TM x 128, BK=64, 4 waves (2x2), 16x16x32 bf16 MFMA.
// Staging: global_load_lds 16B/lane, XOR-swizzled column groups (0 conflicts).
// K-loop: DOUBLE-BUFFERED, statically 2x-unrolled (distinct LDS objects so the
// compiler can't alias them). One barrier per K-step; the next tile's loads
// are issued right after the barrier and stay in flight during compute, so
// the barrier's vmcnt(0) drain hits an already-old load (latency hidden).
// Requires K % 128 == 0.
// ---------------------------------------------------------------------------
template <int MODE, int TM>
__global__ __launch_bounds__(256) void gemm_bt(
    const bf16* __restrict__ A, const bf16* __restrict__ Bt,
    const float* __restrict__ bias, const float* __restrict__ res,
    void* __restrict__ C, int M, int N, int K)
{
    constexpr int MI = TM / 32;                 // frags per wave in M
    __shared__ __align__(16) bf16 As0[TM * 64];
    __shared__ __align__(16) bf16 Bs0[128 * 64];
    __shared__ __align__(16) bf16 As1[TM * 64];
    __shared__ __align__(16) bf16 Bs1[128 * 64];
    const int m0 = blockIdx.x * TM, n0 = blockIdx.y * 128;
    const int t = threadIdx.x;
    const int wave = t >> 6, lane = t & 63, lhi = lane >> 4, llo = lane & 15;
    const int wm = (wave & 1) * (TM / 2), wn = (wave >> 1) * 64;
    const int lrow = lane >> 3;                  // 0..7
    const int lcolsw = ((lane & 7) ^ lrow) * 8;  // swizzled source col group

    // pre-computed global row bases for staging
    const bf16* Ag = A  + (size_t)(m0 + lrow) * K + lcolsw;
    const bf16* Bg = Bt + (size_t)(n0 + lrow) * K + lcolsw;

    f32x4 acc[MI][4];
    for (int i = 0; i < MI; ++i)
        for (int j = 0; j < 4; ++j) acc[i][j] = (f32x4){0.f, 0.f, 0.f, 0.f};

    auto issue = [&](int k0, bf16* As, bf16* Bs) {
        for (int p = 0; p < TM / 32; ++p) {
            int rb = wave * (TM / 4) + p * 8;
            ld16(Ag + (size_t)rb * K + k0, &As[rb * 64]);
        }
        for (int p = 0; p < 4; ++p) {
            int rb = wave * 32 + p * 8;
            ld16(Bg + (size_t)rb * K + k0, &Bs[rb * 64]);
        }
    };
    auto compute = [&](const bf16* As, const bf16* Bs) {
        for (int kk = 0; kk < 64; kk += 32) {
            const int gb = kk >> 3;
            short8 af[MI], bfr[4];
            for (int i = 0; i < MI; ++i) {
                int row = wm + i * 16 + llo;
                af[i] = *(const short8*)&As[row * 64 + (((gb + lhi) ^ (llo & 7)) * 8)];
            }
            for (int i = 0; i < 4; ++i) {
                int row = wn + i * 16 + llo;
                bfr[i] = *(const short8*)&Bs[row * 64 + (((gb + lhi) ^ (llo & 7)) * 8)];
            }
            for (int mi = 0; mi < MI; ++mi)
                for (int ni = 0; ni < 4; ++ni)
                    acc[mi][ni] = __builtin_amdgcn_mfma_f32_16x16x32_bf16(
                        af[mi], bfr[ni], acc[mi][ni], 0, 0, 0);
        }
    };

    issue(0, As0, Bs0);
    for (int k0 = 0; k0 < K; k0 += 128) {
        __syncthreads();                       // As0/Bs0 ready; all waves done with As1/Bs1
        issue(k0 + 64, As1, Bs1);              // in flight during compute below
        compute(As0, Bs0);
        __syncthreads();                       // As1/Bs1 ready; all waves done with As0/Bs0
        if (k0 + 128 < K) issue(k0 + 128, As0, Bs0);
        compute(As1, Bs1);
    }

    for (int mi = 0; mi < MI; ++mi)
        for (int ni = 0; ni < 4; ++ni) {
            int row = m0 + wm + mi * 16 + lhi * 4;
            int col = n0 + wn + ni * 16 + llo;
            float bcol = bias[col];
            for (int r = 0; r < 4; ++r) {
                size_t idx = (size_t)(row + r) * N + col;
                float v = acc[mi][ni][r] + bcol;
                if (MODE == 0) {
                    ((bf16*)C)[idx] = f2bf(v);
                } else if (MODE == 1) {
                    ((float*)C)[idx] = v + res[idx];
                } else if (MODE == 2) {
                    ((bf16*)C)[idx] = f2bf(gelu_f(v));
                } else {
                    ((float*)C)[idx] = v + res[idx];
                }
            }
        }
}

// ---------------------------------------------------------------------------
// Block-local attention: one block per (b, h, seq-block of 64).
// qkv: [8192][3072] bf16 (q | k | v each 1024 wide, head h at col h*64)
// attw: [2048][64][64] fp32 (output 1)   o: [8192][1024] bf16
// ---------------------------------------------------------------------------
__global__ __launch_bounds__(256) void attn_kernel(
    const bf16* __restrict__ qkv, float* __restrict__ attw, bf16* __restrict__ o)
{
    __shared__ __align__(16) bf16 qs[64][LDK];
    __shared__ __align__(16) bf16 ks[64][LDK];
    __shared__ __align__(16) bf16 vs[64][LDK];
    const int gid = blockIdx.x;                 // b*512 + h*32 + blk
    const int blk = gid & 31, h = (gid >> 5) & 15, b = gid >> 9;
    const int t = threadIdx.x, wave = t >> 6, lane = t & 63;
    const int lhi = lane >> 4, llo = lane & 15;
    const int srow = t >> 3, scol = (t & 7) * 8;

    for (int p = 0; p < 2; ++p) {
        int r = p * 32 + srow;
        const bf16* base = qkv + (size_t)(b * 2048 + blk * 64 + r) * 3072 + h * 64 + scol;
        *(short8*)&qs[r][scol] = *(const short8*)(base);
        *(short8*)&ks[r][scol] = *(const short8*)(base + 1024);
        *(short8*)&vs[r][scol] = *(const short8*)(base + 2048);
    }
    __syncthreads();

    // scores: wave handles q-rows [16*wave, 16*wave+16)
    f32x4 sacc[4];
    for (int j = 0; j < 4; ++j) sacc[j] = (f32x4){0.f, 0.f, 0.f, 0.f};
    for (int kk = 0; kk < 64; kk += 32) {
        short8 aq = *(const short8*)&qs[wave * 16 + llo][kk + lhi * 8];
        for (int j = 0; j < 4; ++j) {
            short8 bk = *(const short8*)&ks[j * 16 + llo][kk + lhi * 8];
            sacc[j] = __builtin_amdgcn_mfma_f32_16x16x32_bf16(aq, bk, sacc[j], 0, 0, 0);
        }
    }
    // softmax over 64 cols; row = 16*wave + 4*lhi + r lives in 16 lanes (llo) x 4 j
    float inv[4];
    for (int r = 0; r < 4; ++r) {
        float m = -1e30f;
        for (int j = 0; j < 4; ++j) m = fmaxf(m, sacc[j][r]);
        for (int d = 1; d < 16; d <<= 1) m = fmaxf(m, __shfl_xor(m, d));
        float s = 0.f;
        for (int j = 0; j < 4; ++j) {
            float e = expf((sacc[j][r] - m) * 0.125f);
            sacc[j][r] = e; s += e;
        }
        for (int d = 1; d < 16; d <<= 1) s += __shfl_xor(s, d);
        inv[r] = 1.0f / s;
    }
    __syncthreads();   // everyone done reading qs before we overwrite it with P
    const size_t wbase = (size_t)gid * 4096;
    for (int j = 0; j < 4; ++j)
        for (int r = 0; r < 4; ++r) {
            int row = wave * 16 + lhi * 4 + r, col = j * 16 + llo;
            float pw = sacc[j][r] * inv[r];
            qs[row][col] = f2bf(pw);            // P in A-operand source layout
            attw[wbase + row * 64 + col] = pw;  // output 1 (fp32)
        }
    __syncthreads();

    // O = P @ V
    f32x4 oacc[4];
    for (int nt = 0; nt < 4; ++nt) oacc[nt] = (f32x4){0.f, 0.f, 0.f, 0.f};
    for (int kk = 0; kk < 64; kk += 32) {
        short8 aw = *(const short8*)&qs[wave * 16 + llo][kk + lhi * 8];
        for (int nt = 0; nt < 4; ++nt) {
            short8 bv;
            for (int jj = 0; jj < 8; ++jj)
                bv[jj] = *(const short*)&vs[kk + lhi * 8 + jj][nt * 16 + llo];
            oacc[nt] = __builtin_amdgcn_mfma_f32_16x16x32_bf16(aw, bv, oacc[nt], 0, 0, 0);
        }
    }
    for (int nt = 0; nt < 4; ++nt)
        for (int r = 0; r < 4; ++r) {
            int row = wave * 16 + lhi * 4 + r, col = nt * 16 + llo;
            o[(size_t)(b * 2048 + blk * 64 + row) * 1024 + h * 64 + col] = f2bf(oacc[nt][r]);
        }
}

// ---------------------------------------------------------------------------
extern "C" void kernel_launch(void* const* d_in, const int* in_sizes, int n_in,
                              void* d_out, int out_size, void* d_ws, size_t ws_size,
                              hipStream_t stream)
{
    const float* hidden = (const float*)d_in[0];
    const float* ln1_g  = (const float*)d_in[1];
    const float* ln1_b  = (const float*)d_in[2];
    const float* ln2_g  = (const float*)d_in[3];
    const float* ln2_b  = (const float*)d_in[4];
    const float* wq = (const float*)d_in[5];  const float* bq = (const float*)d_in[6];
    const float* wk = (const float*)d_in[7];  const float* bk = (const float*)d_in[8];
    const float* wv = (const float*)d_in[9];  const float* bv = (const float*)d_in[10];
    const float* wo = (const float*)d_in[11]; const float* bo = (const float*)d_in[12];
    const float* w1 = (const float*)d_in[13]; const float* b1 = (const float*)d_in[14];
    const float* w2 = (const float*)d_in[15]; const float* b2 = (const float*)d_in[16];

    char* ws = (char*)d_ws;
    const size_t MB = 1u << 20;
    // layout (MiB): peak 137 (same as the round-1 layout that ran fine)
    bf16*  wqkvT   = (bf16*)(ws +  0 * MB);  // [3072][1024]  6MB
    bf16*  woT     = (bf16*)(ws +  6 * MB);  // [1024][1024]  2MB
    bf16*  w1T     = (bf16*)(ws +  8 * MB);  // [4096][1024]  8MB
    bf16*  w2T     = (bf16*)(ws + 16 * MB);  // [1024][4096]  8MB
    float* biasQKV = (float*)(ws + 24 * MB); // 12KB
    bf16*  x       = (bf16*)(ws + 25 * MB);  // [8192][1024] 16MB (x1 then x2)
    bf16*  qkv     = (bf16*)(ws + 41 * MB);  // [8192][3072] 48MB (dead after attn)
    float* hbuf    = (float*)(ws + 41 * MB); // [8192][1024] fp32 32MB, overlays qkv
    bf16*  ffc     = (bf16*)(ws + 73 * MB);  // [8192][4096] 64MB: qkv tail + obuf + fresh
    bf16*  obuf    = (bf16*)(ws + 89 * MB);  // [8192][1024] 16MB (dead after gemm<1>)

    float* out0 = (float*)d_out;
    float* attw = (float*)d_out + (size_t)8192 * 1024;

    // 1. weights -> bf16, transposed to [N][K]
    transpose_f32_bf16<<<dim3(16, 16), 256, 0, stream>>>(wq, wqkvT,                 1024, 1024);
    transpose_f32_bf16<<<dim3(16, 16), 256, 0, stream>>>(wk, wqkvT + 1024 * 1024,   1024, 1024);
    transpose_f32_bf16<<<dim3(16, 16), 256, 0, stream>>>(wv, wqkvT + 2*1024*1024,   1024, 1024);
    transpose_f32_bf16<<<dim3(16, 16), 256, 0, stream>>>(wo, woT, 1024, 1024);
    transpose_f32_bf16<<<dim3(64, 16), 256, 0, stream>>>(w1, w1T, 1024, 4096);
    transpose_f32_bf16<<<dim3(16, 64), 256, 0, stream>>>(w2, w2T, 4096, 1024);
    concat_bias<<<12, 256, 0, stream>>>(bq, bk, bv, biasQKV);

    // 2. x1 = LN1(hidden)
    layernorm_k<<<8192, 256, 0, stream>>>(hidden, ln1_g, ln1_b, x);

    // 3. qkv = x1 @ [wq|wk|wv]^T + [bq|bk|bv]   (M=8192, N=3072, K=1024)
    gemm_bt<0, 128><<<dim3(64, 24), 256, 0, stream>>>(x, wqkvT, biasQKV, nullptr, qkv,
                                                      8192, 3072, 1024);

    // 4. block attention -> attw (fp32, output 1), obuf (bf16)
    attn_kernel<<<2048, 256, 0, stream>>>(qkv, attw, obuf);

    // 5. h = obuf @ wo^T + bo + hidden   (fp32; qkv region is dead now)
    gemm_bt<1, 64><<<dim3(128, 8), 256, 0, stream>>>(obuf, woT, bo, hidden, hbuf,
                                                     8192, 1024, 1024);

    // 6. x2 = LN2(h)
    layernorm_k<<<8192, 256, 0, stream>>>(hbuf, ln2_g, ln2_b, x);

    // 7. ff1 = gelu(x2 @ w1^T + b1)   (M=8192, N=4096, K=1024) — full M
    gemm_bt<2, 128><<<dim3(64, 32), 256, 0, stream>>>(x, w1T, b1, nullptr, ffc,
                                                      8192, 4096, 1024);

    // 8. out0 = ff1 @ w2^T + b2 + h   (M=8192, N=1024, K=4096) — full M
    gemm_bt<3, 64><<<dim3(128, 8), 256, 0, stream>>>(ffc, w2T, b2, hbuf, out0,
                                                     8192, 1024, 4096);
}